// Round 2
// baseline (1850.652 us; speedup 1.0000x reference)
//
#include <hip/hip_runtime.h>

typedef unsigned short u16;
typedef short s16x8 __attribute__((ext_vector_type(8)));
typedef float f32x4 __attribute__((ext_vector_type(4)));

__device__ __forceinline__ float u2f(u16 u) {
    union { unsigned int i; float f; } c; c.i = ((unsigned int)u) << 16; return c.f;
}
__device__ __forceinline__ u16 f2u(float f) {
    union { float f; unsigned int i; } c; c.f = f;
    unsigned int x = c.i;
    x += 0x7fffu + ((x >> 16) & 1u);   // RNE
    return (u16)(x >> 16);
}

// ---------------------------------------------------------------------------
// Generic 3x3 SAME conv as 9 tap-GEMM K-slabs, MFMA 16x16x32 bf16.
// in:  padded NHWC bf16 [img][Hp][Wp][Cin]  (1px zero ring)
// wT:  bf16 [9][Npad][Cin]  (pre-transposed, zero-padded rows)
// out: bf16, arbitrary strided NHWC dst via out_off/strides
// Block: 256 thr = 4 waves. BM=128 positions (WT_=1<<WSHIFT cols x 128/WT_ rows).
// ---------------------------------------------------------------------------
template<int BN, int WMW, int WNW, int WSHIFT>
__global__ __launch_bounds__(256, 2)
void conv3x3_mfma(const u16* __restrict__ in, const u16* __restrict__ wT,
                  const float* __restrict__ bias, u16* __restrict__ out,
                  int Cin, int Cout, int Npad, int Wp, int in_img_stride,
                  int tiles_per_img, int xtiles,
                  int ldC, int out_rstride, int out_istride, int out_off,
                  int KC, int relu)
{
    constexpr int WT_    = 1 << WSHIFT;   // cols per M-tile
    constexpr int WMROWS = 128 / WMW;     // rows of C per wave (m)
    constexpr int WNCOLS = BN / WNW;      // cols of C per wave (n)
    constexpr int AM     = WMROWS / 16;
    constexpr int AN     = WNCOLS / 16;
    constexpr int BINSTR = (BN * 64) / 1024;  // 1KB B-chunks

    __shared__ __align__(16) u16 As[128 * 32];
    __shared__ __align__(16) u16 Bs[BN * 32];

    const int tid  = threadIdx.x;
    const int wave = tid >> 6;
    const int lane = tid & 63;
    const int l15  = lane & 15;
    const int quad = lane >> 4;
    const int wm   = wave / WNW;
    const int wn   = wave % WNW;

    const int tile  = blockIdx.x;
    const int n0    = blockIdx.y * BN;
    const int img   = tile / tiles_per_img;
    const int rem   = tile - img * tiles_per_img;
    const int ytile = rem / xtiles;
    const int xt    = rem - ytile * xtiles;
    const int RT    = 128 / WT_;
    const int y0    = ytile * RT;
    const int x0    = xt * WT_;

    // A staging: 8 x 1KB chunks; wave w does chunks {w, w+4}
    const u16* aptr[2];
#pragma unroll
    for (int s = 0; s < 2; ++s) {
        int p = wave + s * 4;
        int e = p * 512 + lane * 8;      // element index in [128][32] tile
        int m = e >> 5;
        int c = e & 31;
        int ry = m >> WSHIFT;
        int xcol = m & (WT_ - 1);
        aptr[s] = in + (long)img * in_img_stride
                     + ((y0 + ry) * Wp + (x0 + xcol)) * Cin + c;
    }
    // B staging: BINSTR x 1KB chunks
    const u16* bptr[2];
    {
        int s = 0;
        for (int q = wave; q < BINSTR; q += 4, ++s) {
            int e = q * 512 + lane * 8;  // element in [BN][32] tile
            int n = e >> 5;
            int k = e & 31;
            bptr[s] = wT + (n0 + n) * Cin + k;
        }
    }

    f32x4 acc[AM][AN];
#pragma unroll
    for (int i = 0; i < AM; ++i)
#pragma unroll
        for (int j = 0; j < AN; ++j) acc[i][j] = {0.f, 0.f, 0.f, 0.f};

    for (int tap = 0; tap < 9; ++tap) {
        const int dy = tap / 3, dx = tap - dy * 3;
        const int aoff_tap = (dy * Wp + dx) * Cin;
        const int boff_tap = tap * Npad * Cin;
        for (int kc = 0; kc < KC; ++kc) {
            const int coff = kc * 32;
#pragma unroll
            for (int s = 0; s < 2; ++s) {
                __builtin_amdgcn_global_load_lds(
                    (const __attribute__((address_space(1))) void*)(aptr[s] + aoff_tap + coff),
                    (__attribute__((address_space(3))) void*)(&As[(wave + s * 4) * 512]),
                    16, 0, 0);
            }
            {
                int s = 0;
                for (int q = wave; q < BINSTR; q += 4, ++s) {
                    __builtin_amdgcn_global_load_lds(
                        (const __attribute__((address_space(1))) void*)(bptr[s] + boff_tap + coff),
                        (__attribute__((address_space(3))) void*)(&Bs[q * 512]),
                        16, 0, 0);
                }
            }
            __syncthreads();

            s16x8 af[AM], bf[AN];
#pragma unroll
            for (int i = 0; i < AM; ++i)
                af[i] = *(const s16x8*)&As[(wm * WMROWS + i * 16 + l15) * 32 + quad * 8];
#pragma unroll
            for (int j = 0; j < AN; ++j)
                bf[j] = *(const s16x8*)&Bs[(wn * WNCOLS + j * 16 + l15) * 32 + quad * 8];
#pragma unroll
            for (int i = 0; i < AM; ++i)
#pragma unroll
                for (int j = 0; j < AN; ++j)
                    acc[i][j] = __builtin_amdgcn_mfma_f32_16x16x32_bf16(
                        af[i], bf[j], acc[i][j], 0, 0, 0);
            __syncthreads();
        }
    }

    // epilogue: C/D layout col=lane&15, row=quad*4+r  (m89/m91-verified)
    const long obase = (long)out_off + (long)img * out_istride;
#pragma unroll
    for (int i = 0; i < AM; ++i) {
        int mb = wm * WMROWS + i * 16 + quad * 4;
#pragma unroll
        for (int j = 0; j < AN; ++j) {
            int n = n0 + wn * WNCOLS + j * 16 + l15;
            if (n < Cout) {
                float bv = bias[n];
#pragma unroll
                for (int r = 0; r < 4; ++r) {
                    int m = mb + r;
                    int ry = m >> WSHIFT, xcol = m & (WT_ - 1);
                    float v = acc[i][j][r] + bv;
                    if (relu) v = fmaxf(v, 0.f);
                    out[obase + (long)(y0 + ry) * out_rstride + (long)(x0 + xcol) * ldC + n] = f2u(v);
                }
            }
        }
    }
}

// ---------------------------------------------------------------------------
// weight transpose+cvt: w fp32 [3,3,Cin,Cout] -> wT bf16 [9][Npad][Cin]
// ---------------------------------------------------------------------------
__global__ void transpose_w(const float* __restrict__ w, u16* __restrict__ wT,
                            int Cin, int Cout, int Npad)
{
    int idx = blockIdx.x * 256 + threadIdx.x;
    int total = 9 * Npad * Cin;
    if (idx >= total) return;
    int cin = idx % Cin;
    int r = idx / Cin;
    int n = r % Npad;
    int tap = r / Npad;
    wT[idx] = (n < Cout) ? f2u(w[(tap * Cin + cin) * Cout + n]) : (u16)0;
}

// combined reg(12) + wt(3) + zero(1) head weights -> bf16 [9][16][256], fp32 bias16
__global__ void transpose_head(const float* __restrict__ regw, const float* __restrict__ wtw,
                               const float* __restrict__ regb, const float* __restrict__ wtb,
                               u16* __restrict__ wT, float* __restrict__ bOut)
{
    int idx = blockIdx.x * 256 + threadIdx.x;
    if (idx < 16)
        bOut[idx] = (idx < 12) ? regb[idx] : (idx < 15 ? wtb[idx - 12] : 0.f);
    if (idx >= 9 * 16 * 256) return;
    int cin = idx & 255;
    int r = idx >> 8;
    int n = r & 15;
    int tap = r >> 4;
    float v = 0.f;
    if (n < 12)      v = regw[(tap * 256 + cin) * 12 + n];
    else if (n < 15) v = wtw[(tap * 256 + cin) * 3 + (n - 12)];
    wT[idx] = f2u(v);
}

// feat1 fp32 [4,256,256,128] -> bf16 pad1 [4,258,258,128] interior
__global__ void cvt_pad(const float* __restrict__ in, u16* __restrict__ out)
{
    int idx = blockIdx.x * 256 + threadIdx.x;  // 4*256*256*16 chunks of 8ch
    if (idx >= 4 * 256 * 256 * 16) return;
    int cc = idx & 15;
    int pos = idx >> 4;
    int x = pos & 255, y = (pos >> 8) & 255, b = pos >> 16;
    const float4* s4 = (const float4*)(in + (size_t)idx * 8);
    float4 a = s4[0], bb = s4[1];
    u16 tmp[8];
    tmp[0] = f2u(a.x);  tmp[1] = f2u(a.y);  tmp[2] = f2u(a.z);  tmp[3] = f2u(a.w);
    tmp[4] = f2u(bb.x); tmp[5] = f2u(bb.y); tmp[6] = f2u(bb.z); tmp[7] = f2u(bb.w);
    *(uint4*)&out[(((b * 258 + y + 1) * 258) + x + 1) * 128 + cc * 8] = *(uint4*)tmp;
}

// classification head: mean -> fc1 -> fc2 -> fc3 -> softmax/argmax  (all fp32)
__global__ __launch_bounds__(256)
void cls_head(const float* __restrict__ feat5,
              const float* fc1w, const float* fc1b,
              const float* fc2w, const float* fc2b,
              const float* fc3w, const float* fc3b,
              float* __restrict__ pred_out, int* __restrict__ cls_out)
{
    int b = blockIdx.x, t = threadIdx.x;
    __shared__ float g[256], h1[256], h2[256], lg[3];
    const float* base = feat5 + b * 65536;
    float s = 0.f;
    for (int p = 0; p < 256; ++p) s += base[p * 256 + t];
    g[t] = s * (1.f / 256.f);
    __syncthreads();
    float a = fc1b[t];
    for (int k = 0; k < 256; ++k) a += g[k] * fc1w[k * 256 + t];
    h1[t] = fmaxf(a, 0.f);
    __syncthreads();
    a = fc2b[t];
    for (int k = 0; k < 256; ++k) a += h1[k] * fc2w[k * 256 + t];
    h2[t] = fmaxf(a, 0.f);
    __syncthreads();
    if (t < 3) {
        float l = fc3b[t];
        for (int k = 0; k < 256; ++k) l += h2[k] * fc3w[k * 3 + t];
        lg[t] = l;
    }
    __syncthreads();
    if (t == 0) {
        float m = fmaxf(lg[0], fmaxf(lg[1], lg[2]));
        float e0 = expf(lg[0] - m), e1 = expf(lg[1] - m), e2 = expf(lg[2] - m);
        float inv = 1.f / (e0 + e1 + e2);
        pred_out[b * 3 + 0] = e0 * inv;
        pred_out[b * 3 + 1] = e1 * inv;
        pred_out[b * 3 + 2] = e2 * inv;
        int best = 0;
        if (lg[1] > lg[best]) best = 1;
        if (lg[2] > lg[best]) best = 2;
        cls_out[b] = best;
    }
}

// bilinear crop: fp32 feat0 [4,512,512,64] + fp32 boxes -> bf16 cropsp [256][34][34][64]
__global__ __launch_bounds__(256)
void crop_kernel(const float* __restrict__ feat0, const float* __restrict__ boxes,
                 u16* __restrict__ cropsp)
{
    int gid = blockIdx.x;           // n*32 + oy
    int oy = gid & 31;
    int n = gid >> 5;
    int b = n >> 6;
    const float* bx = boxes + n * 4;
    float y1 = bx[0], x1 = bx[1], y2 = bx[2], x2 = bx[3];
    float ty = (float)oy * (1.f / 31.f);
    float ys = y1 * 511.f + (ty * (y2 - y1)) * 511.f;
    int y0i = (int)floorf(ys);
    y0i = y0i < 0 ? 0 : (y0i > 510 ? 510 : y0i);
    float wy = ys - (float)y0i;
    int t = threadIdx.x;
    int c = t & 63;
    int xg = t >> 6;
    const float* r0 = feat0 + ((size_t)(b * 512 + y0i) * 512) * 64;
    for (int ox = xg; ox < 32; ox += 4) {
        float tx = (float)ox * (1.f / 31.f);
        float xs = x1 * 511.f + (tx * (x2 - x1)) * 511.f;
        int x0i = (int)floorf(xs);
        x0i = x0i < 0 ? 0 : (x0i > 510 ? 510 : x0i);
        float wx = xs - (float)x0i;
        float v00 = r0[x0i * 64 + c];
        float v01 = r0[(x0i + 1) * 64 + c];
        float v10 = r0[32768 + x0i * 64 + c];
        float v11 = r0[32768 + (x0i + 1) * 64 + c];
        float ca = v00 * (1.f - wy) + v10 * wy;
        float cb = v01 * (1.f - wy) + v11 * wy;
        float val = ca * (1.f - wx) + cb * wx;
        cropsp[((n * 34 + oy + 1) * 34 + ox + 1) * 64 + c] = f2u(val);
    }
}

// per-class gather of bf16 reg/wt head -> fp32 offsets, sizes, weights
__global__ void reg_gather(const u16* __restrict__ head15, const int* __restrict__ cls,
                           float* __restrict__ out)
{
    int idx = blockIdx.x * 256 + threadIdx.x;   // 4*256*256
    if (idx >= 262144) return;
    int b = idx >> 16;
    int cl = cls[b];
    int c4 = cl * 4;
    const u16* p = head15 + (long)idx * 16;
    out[idx * 2 + 0] = u2f(p[c4]);
    out[idx * 2 + 1] = u2f(p[c4 + 1]);
    out[524288 + idx * 2 + 0] = u2f(p[c4 + 2]);
    out[524288 + idx * 2 + 1] = u2f(p[c4 + 3]);
    out[1048576 + idx] = u2f(p[12 + cl]);
}

__global__ void seg_gather(const u16* __restrict__ seg16, const int* __restrict__ cls,
                           float* __restrict__ out)
{
    int idx = blockIdx.x * 256 + threadIdx.x;   // 256*32*32
    if (idx >= 262144) return;
    int n = idx >> 10;
    out[idx] = u2f(seg16[(long)idx * 16 + cls[n >> 6]]);
}

// score head: 4x4 avgpool(bf16 s2p) -> fp32 fc 6144->256 -> 256->256 -> 256->3 -> select
__global__ __launch_bounds__(256)
void score_head(const u16* __restrict__ s2p,
                const float* sd1w, const float* sd1b,
                const float* sd2w, const float* sd2b,
                const float* sd3w, const float* sd3b,
                const int* __restrict__ cls, float* __restrict__ out)
{
    int n = blockIdx.x, t = threadIdx.x;
    __shared__ float pooled[6144];
    __shared__ float h1[256], h2[256];
    const u16* sb = s2p + (long)n * 34 * 34 * 96;
    for (int q = 0; q < 24; ++q) {
        int o = t + 256 * q;
        int c = o % 96;
        int pw = o / 96;
        int wx = pw & 7, hy = pw >> 3;
        float s = 0.f;
        for (int i = 0; i < 4; ++i)
            for (int j = 0; j < 4; ++j)
                s += u2f(sb[((1 + hy * 4 + i) * 34 + (1 + wx * 4 + j)) * 96 + c]);
        pooled[o] = s * 0.0625f;
    }
    __syncthreads();
    float a = sd1b[t];
    for (int k = 0; k < 6144; ++k) a += pooled[k] * sd1w[k * 256 + t];
    h1[t] = fmaxf(a, 0.f);
    __syncthreads();
    a = sd2b[t];
    for (int k = 0; k < 256; ++k) a += h1[k] * sd2w[k * 256 + t];
    h2[t] = fmaxf(a, 0.f);
    __syncthreads();
    if (t == 0) {
        int cl = cls[n >> 6];
        float s = sd3b[cl];
        for (int k = 0; k < 256; ++k) s += h2[k] * sd3w[k * 3 + cl];
        out[n] = s;
    }
}

// ---------------------------------------------------------------------------
extern "C" void kernel_launch(void* const* d_in, const int* in_sizes, int n_in,
                              void* d_out, int out_size, void* d_ws, size_t ws_size,
                              hipStream_t stream)
{
    const float* feat0 = (const float*)d_in[0];
    const float* feat1 = (const float*)d_in[1];
    const float* feat5 = (const float*)d_in[2];
    const float* boxes = (const float*)d_in[3];
    const float* cb1_w = (const float*)d_in[4];  const float* cb1_b = (const float*)d_in[5];
    const float* cb2_w = (const float*)d_in[6];  const float* cb2_b = (const float*)d_in[7];
    const float* reg_w = (const float*)d_in[8];  const float* reg_b = (const float*)d_in[9];
    const float* wt_w  = (const float*)d_in[10]; const float* wt_b  = (const float*)d_in[11];
    const float* fc1_w = (const float*)d_in[12]; const float* fc1_b = (const float*)d_in[13];
    const float* fc2_w = (const float*)d_in[14]; const float* fc2_b = (const float*)d_in[15];
    const float* fc3_w = (const float*)d_in[16]; const float* fc3_b = (const float*)d_in[17];
    const float* sc1_w = (const float*)d_in[18]; const float* sc1_b = (const float*)d_in[19];
    const float* sc2_w = (const float*)d_in[20]; const float* sc2_b = (const float*)d_in[21];
    const float* so_w  = (const float*)d_in[22]; const float* so_b  = (const float*)d_in[23];
    const float* sd1_w = (const float*)d_in[24]; const float* sd1_b = (const float*)d_in[25];
    const float* sd2_w = (const float*)d_in[26]; const float* sd2_b = (const float*)d_in[27];
    const float* sd3_w = (const float*)d_in[28]; const float* sd3_b = (const float*)d_in[29];

    char* ws = (char*)d_ws;
    size_t off = 0;
    auto alloc = [&](size_t bytes) -> char* {
        char* p = ws + off;
        off += (bytes + 255) & ~(size_t)255;
        return p;
    };
    u16* pad1   = (u16*)alloc(68161536);   // region0: later reused as cropsp
    u16* x1p    = (u16*)alloc(136323072);  // region1: later reused as s1p+s2p
    u16* x2p    = (u16*)alloc(136323072);
    u16* head15 = (u16*)alloc(8388608);
    u16* seg16  = (u16*)alloc(8388608);
    u16* cb1T   = (u16*)alloc(589824);
    u16* cb2T   = (u16*)alloc(1179648);
    u16* headT  = (u16*)alloc(73728);
    float* headB = (float*)alloc(64);
    u16* sc1T   = (u16*)alloc(147456);
    u16* sc2T   = (u16*)alloc(221184);
    u16* soT    = (u16*)alloc(27648);
    int* cls    = (int*)alloc(16);
    u16* cropsp = pad1;                    // 37,879,808 B <= 68,161,536
    u16* s1p    = x1p;                     // 56,819,712 B
    u16* s2p    = x1p + 28409856;          // + 56,819,712 B (fits region1)
    float* d_o  = (float*)d_out;

    // weight transposes (tiny)
    transpose_w<<<(9*256*128 + 255)/256, 256, 0, stream>>>(cb1_w, cb1T, 128, 256, 256);
    transpose_w<<<(9*256*256 + 255)/256, 256, 0, stream>>>(cb2_w, cb2T, 256, 256, 256);
    transpose_w<<<(9*128*64  + 255)/256, 256, 0, stream>>>(sc1_w, sc1T, 64, 96, 128);
    transpose_w<<<(9*128*96  + 255)/256, 256, 0, stream>>>(sc2_w, sc2T, 96, 96, 128);
    transpose_w<<<(9*16*96   + 255)/256, 256, 0, stream>>>(so_w,  soT,  96, 3, 16);
    transpose_head<<<(9*16*256 + 255)/256, 256, 0, stream>>>(reg_w, wt_w, reg_b, wt_b, headT, headB);

    // classification branch (also produces cls[] used by all gathers)
    cls_head<<<4, 256, 0, stream>>>(feat5, fc1_w, fc1_b, fc2_w, fc2_b, fc3_w, fc3_b,
                                    d_o + 1310720, cls);

    // regression branch
    hipMemsetAsync(pad1, 0, 68161536, stream);
    cvt_pad<<<16384, 256, 0, stream>>>(feat1, pad1);
    hipMemsetAsync(x1p, 0, 136323072, stream);
    conv3x3_mfma<128,2,2,7><<<dim3(2048,2), 256, 0, stream>>>(
        pad1, cb1T, cb1_b, x1p, 128, 256, 256, 258, 258*258*128, 512, 2,
        256, 258*256, 258*258*256, 259*256, 4, 1);
    hipMemsetAsync(x2p, 0, 136323072, stream);
    conv3x3_mfma<128,2,2,7><<<dim3(2048,2), 256, 0, stream>>>(
        x1p, cb2T, cb2_b, x2p, 256, 256, 256, 258, 258*258*256, 512, 2,
        256, 258*256, 258*258*256, 259*256, 8, 1);
    conv3x3_mfma<16,4,1,7><<<dim3(2048,1), 256, 0, stream>>>(
        x2p, headT, headB, head15, 256, 15, 16, 258, 258*258*256, 512, 2,
        16, 256*16, 256*256*16, 0, 8, 0);
    reg_gather<<<1024, 256, 0, stream>>>(head15, cls, d_o);

    // segmentation branch (reuses region0/region1 after convs above)
    hipMemsetAsync(cropsp, 0, 37879808, stream);
    crop_kernel<<<8192, 256, 0, stream>>>(feat0, boxes, cropsp);
    hipMemsetAsync(s1p, 0, 56819712, stream);
    conv3x3_mfma<128,2,2,5><<<dim3(2048,1), 256, 0, stream>>>(
        cropsp, sc1T, sc1_b, s1p, 64, 96, 128, 34, 34*34*64, 8, 1,
        96, 34*96, 34*34*96, 35*96, 2, 1);
    hipMemsetAsync(s2p, 0, 56819712, stream);
    conv3x3_mfma<128,2,2,5><<<dim3(2048,1), 256, 0, stream>>>(
        s1p, sc2T, sc2_b, s2p, 96, 96, 128, 34, 34*34*96, 8, 1,
        96, 34*96, 34*34*96, 35*96, 3, 1);
    conv3x3_mfma<16,4,1,5><<<dim3(2048,1), 256, 0, stream>>>(
        s2p, soT, so_b, seg16, 96, 3, 16, 34, 34*34*96, 8, 1,
        16, 32*16, 32*32*16, 0, 3, 0);
    seg_gather<<<1024, 256, 0, stream>>>(seg16, cls, d_o + 1310732);
    score_head<<<256, 256, 0, stream>>>(s2p, sd1_w, sd1_b, sd2_w, sd2_b, sd3_w, sd3_b,
                                        cls, d_o + 1572876);
    (void)in_sizes; (void)n_in; (void)out_size; (void)ws_size;
}